// Round 6
// baseline (205.005 us; speedup 1.0000x reference)
//
#include <hip/hip_runtime.h>
#include <hip/hip_bf16.h>

typedef __bf16 bf16;
typedef __attribute__((ext_vector_type(8))) __bf16 bf16x8;
typedef __attribute__((ext_vector_type(4))) __bf16 bf16x4;
typedef __attribute__((ext_vector_type(2))) __bf16 bf16x2;
typedef __attribute__((ext_vector_type(4))) float f32x4;
typedef __attribute__((ext_vector_type(16))) float f32x16;

// Problem constants: B=4, T=2048, E=1024, H=16, HD=64
// g = b*2048+t in [0,8192); bh' = (g&3)*16 + (e>>6); t' = g>>2; d = e&63
// Q/K layout: [bh'][t'][d] flat = bh*131072 + t*64 + d
// VT layout:  [bh'][d][t'] flat = bh*131072 + d*2048 + t
// Attn output flat [bh'][t'][d] IS the row-major (8192,1024) A-matrix of GEMM2.

typedef const __attribute__((address_space(1))) void* gas_ptr;
typedef __attribute__((address_space(3))) void* las_ptr;

__device__ __forceinline__ void gl_lds16(const void* g, void* s) {
    __builtin_amdgcn_global_load_lds((gas_ptr)g, (las_ptr)s, 16, 0, 0);
}

__device__ __forceinline__ uint32_t pk2(float a, float b) {
    bf16x2 t; t[0] = (bf16)a; t[1] = (bf16)b;
    return __builtin_bit_cast(uint32_t, t);
}

#define MFMA32(a, b, c) __builtin_amdgcn_mfma_f32_32x32x16_bf16(a, b, c, 0, 0, 0)
#define MFMA16(a, b, c) __builtin_amdgcn_mfma_f32_16x16x32_bf16(a, b, c, 0, 0, 0)

__global__ __launch_bounds__(256) void cvt_f32_bf16(const float* __restrict__ in,
                                                    bf16* __restrict__ out, int n) {
    int i = (blockIdx.x * 256 + threadIdx.x) * 4;
    if (i >= n) return;
    float4 v = *(const float4*)(in + i);
    bf16x4 o;
    o[0] = (bf16)v.x; o[1] = (bf16)v.y; o[2] = (bf16)v.z; o[3] = (bf16)v.w;
    *(bf16x4*)(out + i) = o;
}

// ------------------- GEMM1: 256x256 tile, BK=64, 8-phase schedule ------------
// A (8192x1024 bf16 row-major) * Bw^T (3072x1024 bf16 row-major) + bias,
// scatter epilogue to Q (x0.125) / K / VT. 512 threads = 8 waves (2M x 4N).
// Wave-banded quadrants: wave rows {wm*64 + mh*128}, cols {wn*32 + nh*128} so
// each phase's LDS-half dependency is wave-uniform:
//   P0: A0xB0  P1: A0xB1  P2: A1xB1  P3: A1xB0
// Stage issue (for kt+1): P0->A0, P1->B0, P2->B1, P3->A1.
// Counted waits: vmcnt(2) end-P0 (drains B1,A1 of current), vmcnt(4) end-P3
// (drains A0,B0 of next). Never vmcnt(0) in the loop.

__device__ __forceinline__ void stage_half(const char* gp, char* lp, int tid) {
#pragma unroll
    for (int g = 0; g < 2; ++g) {
        const int o = (g * 512 + tid) * 16;
        const int row = o >> 7;
        gl_lds16(gp + row * 2048 + ((o & 127) ^ ((row & 7) << 4)), lp + o);
    }
}

__device__ __forceinline__ bf16x8 rdf(const char* half, int row, int ks, int fcb) {
    return *(const bf16x8*)(half + row * 128 + ((ks * 64 + fcb) ^ ((row & 7) << 4)));
}

__global__ __launch_bounds__(512, 1) void gemm1_8ph(const bf16* __restrict__ A,
                                                    const bf16* __restrict__ Bw,
                                                    const float* __restrict__ bias,
                                                    bf16* __restrict__ Qb,
                                                    bf16* __restrict__ Kb,
                                                    bf16* __restrict__ VTb) {
    __shared__ __align__(16) char lds[2][4][16384];  // halves: 0=A0,1=A1,2=B0,3=B1

    const int tid = threadIdx.x;
    const int l = tid & 63;
    const int w = tid >> 6;
    const int wm = w >> 2;           // 0..1
    const int wn = w & 3;            // 0..3
    const int fr = l & 15;
    const int fcb = 16 * (l >> 4);   // byte col within 64B k-slice
    const int bm0 = blockIdx.x * 256;
    const int bn0 = blockIdx.y * 256;

    const char* Ab = (const char*)A + (size_t)bm0 * 2048;
    const char* Bb = (const char*)Bw + (size_t)bn0 * 2048;

    f32x4 acc[8][4] = {};
    bf16x8 Afr[4][2], Bfr[4][2];

    // prologue: stage kt=0 (all 4 halves) into buf 0
    stage_half(Ab, lds[0][0], tid);
    stage_half(Ab + 128 * 2048, lds[0][1], tid);
    stage_half(Bb, lds[0][2], tid);
    stage_half(Bb + 128 * 2048, lds[0][3], tid);
    asm volatile("s_waitcnt vmcnt(0)" ::: "memory");
    __builtin_amdgcn_s_barrier();

    for (int kt = 0; kt < 16; ++kt) {
        const char (&rb)[4][16384] = lds[kt & 1];
        char (&wb)[4][16384] = lds[(kt + 1) & 1];
        const int k1b = (kt + 1) * 128;       // byte col offset of next K-tile
        const bool st = (kt + 1) < 16;

        // ---------------- P0: read A0-band + B0-band; stage A0(next) --------
#pragma unroll
        for (int ml = 0; ml < 4; ++ml) {
            const int r = wm * 64 + ml * 16 + fr;
            Afr[ml][0] = rdf(rb[0], r, 0, fcb);
            Afr[ml][1] = rdf(rb[0], r, 1, fcb);
        }
#pragma unroll
        for (int nl = 0; nl < 2; ++nl) {
            const int r = wn * 32 + nl * 16 + fr;
            Bfr[nl][0] = rdf(rb[2], r, 0, fcb);
            Bfr[nl][1] = rdf(rb[2], r, 1, fcb);
        }
        if (st) stage_half(Ab + k1b, wb[0], tid);
        asm volatile("" ::: "memory");
        __builtin_amdgcn_s_barrier();
        __builtin_amdgcn_s_setprio(1);
#pragma unroll
        for (int ml = 0; ml < 4; ++ml)
#pragma unroll
            for (int nl = 0; nl < 2; ++nl) {
                acc[ml][nl] = MFMA16(Afr[ml][0], Bfr[nl][0], acc[ml][nl]);
                acc[ml][nl] = MFMA16(Afr[ml][1], Bfr[nl][1], acc[ml][nl]);
            }
        __builtin_amdgcn_s_setprio(0);
        asm volatile("s_waitcnt vmcnt(2)" ::: "memory");
        __builtin_amdgcn_s_barrier();

        // ---------------- P1: read B1-band; stage B0(next) ------------------
#pragma unroll
        for (int nl = 0; nl < 2; ++nl) {
            const int r = wn * 32 + nl * 16 + fr;
            Bfr[2 + nl][0] = rdf(rb[3], r, 0, fcb);
            Bfr[2 + nl][1] = rdf(rb[3], r, 1, fcb);
        }
        if (st) stage_half(Bb + k1b, wb[2], tid);
        asm volatile("" ::: "memory");
        __builtin_amdgcn_s_barrier();
        __builtin_amdgcn_s_setprio(1);
#pragma unroll
        for (int ml = 0; ml < 4; ++ml)
#pragma unroll
            for (int nl = 0; nl < 2; ++nl) {
                acc[ml][2 + nl] = MFMA16(Afr[ml][0], Bfr[2 + nl][0], acc[ml][2 + nl]);
                acc[ml][2 + nl] = MFMA16(Afr[ml][1], Bfr[2 + nl][1], acc[ml][2 + nl]);
            }
        __builtin_amdgcn_s_setprio(0);
        asm volatile("" ::: "memory");
        __builtin_amdgcn_s_barrier();

        // ---------------- P2: read A1-band; stage B1(next) ------------------
#pragma unroll
        for (int ml = 0; ml < 4; ++ml) {
            const int r = wm * 64 + ml * 16 + fr;
            Afr[ml][0] = rdf(rb[1], r, 0, fcb);
            Afr[ml][1] = rdf(rb[1], r, 1, fcb);
        }
        if (st) stage_half(Bb + 128 * 2048 + k1b, wb[3], tid);
        asm volatile("" ::: "memory");
        __builtin_amdgcn_s_barrier();
        __builtin_amdgcn_s_setprio(1);
#pragma unroll
        for (int ml = 0; ml < 4; ++ml)
#pragma unroll
            for (int nl = 0; nl < 2; ++nl) {
                acc[4 + ml][2 + nl] = MFMA16(Afr[ml][0], Bfr[2 + nl][0], acc[4 + ml][2 + nl]);
                acc[4 + ml][2 + nl] = MFMA16(Afr[ml][1], Bfr[2 + nl][1], acc[4 + ml][2 + nl]);
            }
        __builtin_amdgcn_s_setprio(0);
        asm volatile("" ::: "memory");
        __builtin_amdgcn_s_barrier();

        // ---------------- P3: no reads; stage A1(next) ----------------------
        if (st) stage_half(Ab + 128 * 2048 + k1b, wb[1], tid);
        asm volatile("" ::: "memory");
        __builtin_amdgcn_s_barrier();
        __builtin_amdgcn_s_setprio(1);
#pragma unroll
        for (int ml = 0; ml < 4; ++ml)
#pragma unroll
            for (int nl = 0; nl < 2; ++nl) {
                acc[4 + ml][nl] = MFMA16(Afr[ml][0], Bfr[nl][0], acc[4 + ml][nl]);
                acc[4 + ml][nl] = MFMA16(Afr[ml][1], Bfr[nl][1], acc[4 + ml][nl]);
            }
        __builtin_amdgcn_s_setprio(0);
        asm volatile("s_waitcnt vmcnt(4)" ::: "memory");
        __builtin_amdgcn_s_barrier();
    }

    // scatter epilogue: QKV layout transform + bias (+0.125 scale on Q cols)
    const int rj = (l >> 4) * 4;
    const int cn = l & 15;
#pragma unroll
    for (int m8 = 0; m8 < 8; ++m8) {
        const int gm_b = bm0 + (m8 >> 2) * 128 + wm * 64 + (m8 & 3) * 16 + rj;
#pragma unroll
        for (int n = 0; n < 4; ++n) {
            const int gn = bn0 + (n >> 1) * 128 + wn * 32 + (n & 1) * 16 + cn;
            const float bv = bias[gn];
            const int sec = gn >> 10;
            const int e = gn & 1023;
            const int eh = e >> 6;
            const int ed = e & 63;
#pragma unroll
            for (int j = 0; j < 4; ++j) {
                const int gm = gm_b + j;
                const float v = acc[m8][n][j] + bv;
                const int bh = ((gm & 3) << 4) + eh;
                const int t = gm >> 2;
                if (sec == 0) {
                    Qb[bh * 131072 + t * 64 + ed] = (bf16)(v * 0.125f);
                } else if (sec == 1) {
                    Kb[bh * 131072 + t * 64 + ed] = (bf16)v;
                } else {
                    VTb[bh * 131072 + ed * 2048 + t] = (bf16)v;
                }
            }
        }
    }
}

// ------------------- GEMM2: m97-structure 128x128 (unchanged) ----------------
__global__ __launch_bounds__(256) void gemm_bt(const bf16* __restrict__ A,
                                               const bf16* __restrict__ Bw,
                                               const float* __restrict__ bias,
                                               float* __restrict__ Cout) {
    __shared__ bf16 As[128 * 32];
    __shared__ bf16 Bs[128 * 32];
    const int tid = threadIdx.x;
    const int l = tid & 63;
    const int w = tid >> 6;
    const int bm0 = blockIdx.x * 128;
    const int bn0 = blockIdx.y * 128;
    const int wr = (w >> 1) * 64;
    const int wc = (w & 1) * 64;
    const int fr_row = l & 15;
    const int fr_col = 8 * (l >> 4);

    f32x4 acc[4][4] = {};

    const bf16* Abase = A + (size_t)bm0 * 1024;
    const bf16* Bbase = Bw + (size_t)bn0 * 1024;

    for (int k0 = 0; k0 < 1024; k0 += 32) {
        __syncthreads();
#pragma unroll
        for (int p = 0; p < 2; ++p) {
            int ei = (p * 256 + tid) * 8;
            int row = ei >> 5;
            int col = ei & 31;
            gl_lds16(Abase + row * 1024 + k0 + col, (char*)As + ei * 2);
            gl_lds16(Bbase + row * 1024 + k0 + col, (char*)Bs + ei * 2);
        }
        __syncthreads();
        bf16x8 af[4], bfr[4];
#pragma unroll
        for (int m = 0; m < 4; ++m)
            af[m] = *(const bf16x8*)&As[(wr + m * 16 + fr_row) * 32 + fr_col];
#pragma unroll
        for (int n = 0; n < 4; ++n)
            bfr[n] = *(const bf16x8*)&Bs[(wc + n * 16 + fr_row) * 32 + fr_col];
#pragma unroll
        for (int m = 0; m < 4; ++m)
#pragma unroll
            for (int n = 0; n < 4; ++n)
                acc[m][n] = MFMA16(af[m], bfr[n], acc[m][n]);
    }

    const int rj = (l >> 4) * 4;
    const int cn = l & 15;
#pragma unroll
    for (int m = 0; m < 4; ++m) {
#pragma unroll
        for (int n = 0; n < 4; ++n) {
            const int gn = bn0 + wc + n * 16 + cn;
            const float bv = bias[gn];
#pragma unroll
            for (int j = 0; j < 4; ++j) {
                const int gm = bm0 + wr + m * 16 + rj + j;
                Cout[(size_t)gm * 1024 + gn] = acc[m][n][j] + bv;
            }
        }
    }
}

// Flash attention: 4 warps x 32 q-rows (128 q/block), KVBLK=64, 32x32x16 MFMA,
// swapped QK^T (lane owns one q-row). R2-proven arithmetic (base-e __expf,
// unconditional rescale, __shfl_xor reductions) in the 4-warp geometry shell.
__global__ __launch_bounds__(256) void attn_fwd4(const bf16* __restrict__ Qb,
                                                 const bf16* __restrict__ Kb,
                                                 const bf16* __restrict__ VTb,
                                                 const int* __restrict__ kpm,
                                                 bf16* __restrict__ Ob) {
    __shared__ __align__(16) char Ks[2][8192];  // [64 keys][64 d] bf16, XOR-swizzled
    __shared__ __align__(16) char Vs[2][8192];  // [64 d][64 keys] bf16, XOR-swizzled
    __shared__ int s_len;

    const int tid = threadIdx.x;
    const int l = tid & 63;
    const int w = tid >> 6;
    const int hi = l >> 5;
    const int l31 = l & 31;

    // Remap: xcd = bid&7 -> 8 bh per XCD (K+V 4MB = one L2); heavy q-tiles first.
    const int bid = blockIdx.x;
    const int j = bid >> 3;
    const int bh = (bid & 7) * 8 + (j & 7);
    const int p = 15 - (j >> 3);
    const int qt0 = p * 128;
    const int c = bh >> 4;

    if (tid == 0) s_len = 2048;
    __syncthreads();
    {
        // monotone tail padding: find first masked index
        const int base = c * 2048 + tid * 8;
        int4 a = *(const int4*)(kpm + base);
        int4 b = *(const int4*)(kpm + base + 4);
        int lm = 2048;
        if (b.w) lm = tid * 8 + 7;
        if (b.z) lm = tid * 8 + 6;
        if (b.y) lm = tid * 8 + 5;
        if (b.x) lm = tid * 8 + 4;
        if (a.w) lm = tid * 8 + 3;
        if (a.z) lm = tid * 8 + 2;
        if (a.y) lm = tid * 8 + 1;
        if (a.x) lm = tid * 8 + 0;
        if (lm < 2048) atomicMin(&s_len, lm);
    }
    __syncthreads();
    const int len = s_len;

    const int nt = min(2 * p + 2, (len + 63) >> 6);   // block tile count
    const int wt = min(2 * p + (w >> 1) + 1, nt);     // this warp's tile count

    const int qg = qt0 + w * 32 + l31;                // this lane's q row
    bf16x8 qa[4];                                     // Q as B-operand frags
    const bf16* Qrow = Qb + (size_t)bh * 131072 + (size_t)qg * 64 + hi * 8;
#pragma unroll
    for (int ks = 0; ks < 4; ++ks) qa[ks] = *(const bf16x8*)(Qrow + ks * 16);

    f32x16 o0 = {}, o1 = {};                          // O^T accs: [d-sub][q]
    float mr = -1e30f, lr = 0.f;

    const char* Kg = (const char*)(Kb + (size_t)bh * 131072);
    const char* Vg = (const char*)(VTb + (size_t)bh * 131072);
    const int srow = tid >> 3;                 // staged row within 32-row group
    const int sbcol = (tid & 7) * 16;          // byte col within 128B row
    const int ldst = tid * 16;                 // linear LDS dest (gl_lds rule)

#pragma unroll
    for (int g = 0; g < 2; ++g) {
        const int row = g * 32 + srow;
        const int scol = sbcol ^ ((row & 7) << 4);    // inverse-swizzle on SOURCE
        gl_lds16(Kg + row * 128 + scol, &Ks[0][g * 4096 + ldst]);
        gl_lds16(Vg + row * 4096 + scol, &Vs[0][g * 4096 + ldst]);
    }

    const int rbase = l31 * 128 + hi * 16;     // fragment read base (row<32)
    const int rxor = (l31 & 7) << 4;           // swizzle on READ

    int cur = 0;
    for (int kt = 0; kt < nt; ++kt) {
        __syncthreads();  // buf[cur] loads drained; prior reads of buf[cur^1] done
        if (kt + 1 < nt) {
            const int nk = (kt + 1) * 64;
#pragma unroll
            for (int g = 0; g < 2; ++g) {
                const int row = g * 32 + srow;
                const int scol = sbcol ^ ((row & 7) << 4);
                gl_lds16(Kg + (nk + row) * 128 + scol, &Ks[cur ^ 1][g * 4096 + ldst]);
                gl_lds16(Vg + row * 4096 + nk * 2 + scol, &Vs[cur ^ 1][g * 4096 + ldst]);
            }
        }
        if (kt < wt) {
            const int kt0 = kt * 64;
            // S' = K·Q^T : lane holds S[key][q=l31] for 32 keys (16 regs x 2 subtiles)
            f32x16 s0 = {}, s1 = {};
#pragma unroll
            for (int ks = 0; ks < 4; ++ks) {
                bf16x8 ka0 = *(const bf16x8*)&Ks[cur][(rbase + ks * 32) ^ rxor];
                bf16x8 ka1 = *(const bf16x8*)&Ks[cur][(4096 + rbase + ks * 32) ^ rxor];
                s0 = MFMA32(ka0, qa[ks], s0);
                s1 = MFMA32(ka1, qa[ks], s1);
            }
            const bool full = (kt0 + 63 <= qt0 + w * 32) && (kt0 + 64 <= len);
            if (!full) {
                const int kmax = min(qg, len - 1) - kt0;  // local key bound
#pragma unroll
                for (int r = 0; r < 16; ++r) {
                    const int kl = (r & 3) + 8 * (r >> 2) + 4 * hi;
                    if (kl > kmax) s0[r] = -1e30f;
                    if (kl + 32 > kmax) s1[r] = -1e30f;
                }
            }
            // row max: 31 in-lane + 1 half-swap
            float mx = s0[0];
#pragma unroll
            for (int r = 1; r < 16; ++r) mx = fmaxf(mx, s0[r]);
#pragma unroll
            for (int r = 0; r < 16; ++r) mx = fmaxf(mx, s1[r]);
            mx = fmaxf(mx, __shfl_xor(mx, 32, 64));
            const float mn = fmaxf(mr, mx);
            const float al = __expf(mr - mn);
            mr = mn;
            float sum = 0.f;
#pragma unroll
            for (int r = 0; r < 16; ++r) { s0[r] = __expf(s0[r] - mr); sum += s0[r]; }
#pragma unroll
            for (int r = 0; r < 16; ++r) { s1[r] = __expf(s1[r] - mr); sum += s1[r]; }
            sum += __shfl_xor(sum, 32, 64);
            lr = lr * al + sum;
#pragma unroll
            for (int r = 0; r < 16; ++r) { o0[r] *= al; o1[r] *= al; }
            // pack P rows to bf16 pairs: pw[kk*8 + u*2 + h] = keys 32kk+8u+4hi+{2h,2h+1}
            uint32_t pw[16];
#pragma unroll
            for (int u = 0; u < 4; ++u) {
#pragma unroll
                for (int h = 0; h < 2; ++h) {
                    pw[u * 2 + h] = pk2(s0[4 * u + 2 * h], s0[4 * u + 2 * h + 1]);
                    pw[8 + u * 2 + h] = pk2(s1[4 * u + 2 * h], s1[4 * u + 2 * h + 1]);
                }
            }
            // PV: O^T += V^T · P^T, P B-frags assembled via one half-swap per ks
#pragma unroll
            for (int ks = 0; ks < 4; ++ks) {
                const int kk = ks >> 1;
                const int uA2 = (ks & 1) * 4;
                const uint32_t oA0 = pw[kk * 8 + uA2 + 0], oA1 = pw[kk * 8 + uA2 + 1];
                const uint32_t oB0 = pw[kk * 8 + uA2 + 2], oB1 = pw[kk * 8 + uA2 + 3];
                const uint32_t s0w = hi ? oA0 : oB0;
                const uint32_t s1w = hi ? oA1 : oB1;
                const uint32_t r0 = (uint32_t)__shfl_xor((int)s0w, 32, 64);
                const uint32_t r1 = (uint32_t)__shfl_xor((int)s1w, 32, 64);
                union { uint32_t u[4]; bf16x8 v; } pb;
                pb.u[0] = hi ? r0 : oA0;
                pb.u[1] = hi ? r1 : oA1;
                pb.u[2] = hi ? oB0 : r0;
                pb.u[3] = hi ? oB1 : r1;
                bf16x8 va0 = *(const bf16x8*)&Vs[cur][(rbase + ks * 32) ^ rxor];
                bf16x8 va1 = *(const bf16x8*)&Vs[cur][(4096 + rbase + ks * 32) ^ rxor];
                o0 = MFMA32(va0, pb.v, o0);
                o1 = MFMA32(va1, pb.v, o1);
            }
        }
        cur ^= 1;
    }
    const float inv = 1.f / lr;
    bf16* Orow = Ob + (size_t)bh * 131072 + (size_t)qg * 64;
#pragma unroll
    for (int r = 0; r < 16; ++r) {
        const int d = (r & 3) + 8 * (r >> 2) + 4 * hi;
        Orow[d] = (bf16)(o0[r] * inv);
        Orow[32 + d] = (bf16)(o1[r] * inv);
    }
}

extern "C" void kernel_launch(void* const* d_in, const int* in_sizes, int n_in,
                              void* d_out, int out_size, void* d_ws, size_t ws_size,
                              hipStream_t stream) {
    const float* x = (const float*)d_in[0];
    const int* kpm = (const int*)d_in[1];
    // d_in[2] attn_mask: exactly causal triu(k=1) -> applied analytically
    const float* wi = (const float*)d_in[3];
    const float* bi = (const float*)d_in[4];
    const float* wo = (const float*)d_in[5];
    const float* bo = (const float*)d_in[6];
    float* out = (float*)d_out;

    char* ws = (char*)d_ws;
    bf16* Qb  = (bf16*)(ws + (size_t)0);
    bf16* Kb  = (bf16*)(ws + ((size_t)16 << 20));
    bf16* VTb = (bf16*)(ws + ((size_t)32 << 20));
    bf16* xbf = (bf16*)(ws + ((size_t)48 << 20));
    bf16* Ob  = xbf;  // alias: x_bf16 dead after GEMM1
    bf16* wib = (bf16*)(ws + ((size_t)64 << 20));
    bf16* wob = (bf16*)(ws + ((size_t)70 << 20));

    cvt_f32_bf16<<<8192, 256, 0, stream>>>(x, xbf, 8388608);
    cvt_f32_bf16<<<3072, 256, 0, stream>>>(wi, wib, 3145728);
    cvt_f32_bf16<<<1024, 256, 0, stream>>>(wo, wob, 1048576);

    gemm1_8ph<<<dim3(32, 12), 512, 0, stream>>>(xbf, wib, bi, Qb, Kb, VTb);
    attn_fwd4<<<1024, 256, 0, stream>>>(Qb, Kb, VTb, kpm, Ob);
    gemm_bt<<<dim3(64, 8), 256, 0, stream>>>(Ob, wob, bo, out);
}

// Round 7
// 189.491 us; speedup vs baseline: 1.0819x; 1.0819x over previous
//
#include <hip/hip_runtime.h>
#include <hip/hip_bf16.h>
#include <math.h>

typedef __bf16 bf16;
typedef __attribute__((ext_vector_type(8))) __bf16 bf16x8;
typedef __attribute__((ext_vector_type(4))) __bf16 bf16x4;
typedef __attribute__((ext_vector_type(2))) __bf16 bf16x2;
typedef __attribute__((ext_vector_type(4))) float f32x4;
typedef __attribute__((ext_vector_type(16))) float f32x16;

// Problem constants: B=4, T=2048, E=1024, H=16, HD=64
// g = b*2048+t in [0,8192); bh' = (g&3)*16 + (e>>6); t' = g>>2; d = e&63
// Q/K layout: [bh'][t'][d] flat = bh*131072 + t*64 + d
// VT layout:  [bh'][d][t'] flat = bh*131072 + d*2048 + t
// Attn output flat [bh'][t'][d] IS the row-major (8192,1024) A-matrix of GEMM2.
// Softmax runs base-2: Q pre-scaled by 0.125*log2(e) in the GEMM1 epilogue.

typedef const __attribute__((address_space(1))) void* gas_ptr;
typedef __attribute__((address_space(3))) void* las_ptr;

__device__ __forceinline__ void gl_lds16(const void* g, void* s) {
    __builtin_amdgcn_global_load_lds((gas_ptr)g, (las_ptr)s, 16, 0, 0);
}

__device__ __forceinline__ uint32_t pk2(float a, float b) {
    bf16x2 t; t[0] = (bf16)a; t[1] = (bf16)b;
    return __builtin_bit_cast(uint32_t, t);
}

#if __has_builtin(__builtin_amdgcn_exp2f)
__device__ __forceinline__ float ex2(float x) { return __builtin_amdgcn_exp2f(x); }
#else
__device__ __forceinline__ float ex2(float x) { return exp2f(x); }
#endif

#define MFMA32(a, b, c) __builtin_amdgcn_mfma_f32_32x32x16_bf16(a, b, c, 0, 0, 0)
#define MFMA16(a, b, c) __builtin_amdgcn_mfma_f32_16x16x32_bf16(a, b, c, 0, 0, 0)

__global__ __launch_bounds__(256) void cvt_f32_bf16(const float* __restrict__ in,
                                                    bf16* __restrict__ out, int n) {
    int i = (blockIdx.x * 256 + threadIdx.x) * 4;
    if (i >= n) return;
    float4 v = *(const float4*)(in + i);
    bf16x4 o;
    o[0] = (bf16)v.x; o[1] = (bf16)v.y; o[2] = (bf16)v.z; o[3] = (bf16)v.w;
    *(bf16x4*)(out + i) = o;
}

// C = A(bf16, MxK row-major) * B^T(bf16, NxK row-major) + bias  (m97 structure)
// EPI 0: qkv scatter to Q (x 0.125*log2e), K, VT buffers as bf16
// EPI 1: plain fp32 store to Cout
template <int EPI>
__global__ __launch_bounds__(256) void gemm_bt(const bf16* __restrict__ A,
                                               const bf16* __restrict__ Bw,
                                               const float* __restrict__ bias,
                                               bf16* __restrict__ Qb,
                                               bf16* __restrict__ Kb,
                                               bf16* __restrict__ VTb,
                                               float* __restrict__ Cout) {
    __shared__ bf16 As[128 * 32];
    __shared__ bf16 Bs[128 * 32];
    const int tid = threadIdx.x;
    const int l = tid & 63;
    const int w = tid >> 6;
    const int bm0 = blockIdx.x * 128;
    const int bn0 = blockIdx.y * 128;
    const int wr = (w >> 1) * 64;
    const int wc = (w & 1) * 64;
    const int fr_row = l & 15;
    const int fr_col = 8 * (l >> 4);

    f32x4 acc[4][4] = {};

    const bf16* Abase = A + (size_t)bm0 * 1024;
    const bf16* Bbase = Bw + (size_t)bn0 * 1024;

    for (int k0 = 0; k0 < 1024; k0 += 32) {
        __syncthreads();
#pragma unroll
        for (int p = 0; p < 2; ++p) {
            int ei = (p * 256 + tid) * 8;
            int row = ei >> 5;
            int col = ei & 31;
            gl_lds16(Abase + row * 1024 + k0 + col, (char*)As + ei * 2);
            gl_lds16(Bbase + row * 1024 + k0 + col, (char*)Bs + ei * 2);
        }
        __syncthreads();
        bf16x8 af[4], bfr[4];
#pragma unroll
        for (int m = 0; m < 4; ++m)
            af[m] = *(const bf16x8*)&As[(wr + m * 16 + fr_row) * 32 + fr_col];
#pragma unroll
        for (int n = 0; n < 4; ++n)
            bfr[n] = *(const bf16x8*)&Bs[(wc + n * 16 + fr_row) * 32 + fr_col];
#pragma unroll
        for (int m = 0; m < 4; ++m)
#pragma unroll
            for (int n = 0; n < 4; ++n)
                acc[m][n] = MFMA16(af[m], bfr[n], acc[m][n]);
    }

    const int rj = (l >> 4) * 4;
    const int cn = l & 15;
#pragma unroll
    for (int m = 0; m < 4; ++m) {
#pragma unroll
        for (int n = 0; n < 4; ++n) {
            const int gn = bn0 + wc + n * 16 + cn;
            const float bv = bias[gn];
            if (EPI == 0) {
                const int sec = bn0 >> 10;
                const int e = gn & 1023;
                const int eh = e >> 6;
                const int ed = e & 63;
#pragma unroll
                for (int j = 0; j < 4; ++j) {
                    const int gm = bm0 + wr + m * 16 + rj + j;
                    const float v = acc[m][n][j] + bv;
                    const int bh = ((gm & 3) << 4) + eh;
                    const int t = gm >> 2;
                    if (sec == 0) {
                        // 0.125 (hd^-0.5) * log2(e): base-2 softmax domain
                        Qb[bh * 131072 + t * 64 + ed] = (bf16)(v * 0.18033688f);
                    } else if (sec == 1) {
                        Kb[bh * 131072 + t * 64 + ed] = (bf16)v;
                    } else {
                        VTb[bh * 131072 + ed * 2048 + t] = (bf16)v;
                    }
                }
            } else {
#pragma unroll
                for (int j = 0; j < 4; ++j) {
                    const int gm = bm0 + wr + m * 16 + rj + j;
                    Cout[(size_t)gm * 1024 + gn] = acc[m][n][j] + bv;
                }
            }
        }
    }
}

// Flash attention: 4 warps x 32 q-rows (128 q/block), KVBLK=64, 32x32x16 MFMA,
// swapped QK^T (lane owns one q-row), base-2 softmax + defer-max (THR=8),
// __shfl_xor for ALL cross-lane exchanges (no permlane anywhere).
__global__ __launch_bounds__(256) void attn_fwd5(const bf16* __restrict__ Qb,
                                                 const bf16* __restrict__ Kb,
                                                 const bf16* __restrict__ VTb,
                                                 const int* __restrict__ kpm,
                                                 bf16* __restrict__ Ob) {
    __shared__ __align__(16) char Ks[2][8192];  // [64 keys][64 d] bf16, XOR-swizzled
    __shared__ __align__(16) char Vs[2][8192];  // [64 d][64 keys] bf16, XOR-swizzled
    __shared__ int s_len;

    const int tid = threadIdx.x;
    const int l = tid & 63;
    const int w = tid >> 6;
    const int hi = l >> 5;
    const int l31 = l & 31;

    // Remap: xcd = bid&7 -> 8 bh per XCD (K+V 4MB = one L2); heavy q-tiles first.
    const int bid = blockIdx.x;
    const int j = bid >> 3;
    const int bh = (bid & 7) * 8 + (j & 7);
    const int p = 15 - (j >> 3);
    const int qt0 = p * 128;
    const int c = bh >> 4;

    if (tid == 0) s_len = 2048;
    __syncthreads();
    {
        // monotone tail padding: find first masked index
        const int base = c * 2048 + tid * 8;
        int4 a = *(const int4*)(kpm + base);
        int4 b = *(const int4*)(kpm + base + 4);
        int lm = 2048;
        if (b.w) lm = tid * 8 + 7;
        if (b.z) lm = tid * 8 + 6;
        if (b.y) lm = tid * 8 + 5;
        if (b.x) lm = tid * 8 + 4;
        if (a.w) lm = tid * 8 + 3;
        if (a.z) lm = tid * 8 + 2;
        if (a.y) lm = tid * 8 + 1;
        if (a.x) lm = tid * 8 + 0;
        if (lm < 2048) atomicMin(&s_len, lm);
    }
    __syncthreads();
    const int len = s_len;

    const int nt = min(2 * p + 2, (len + 63) >> 6);   // block tile count
    const int wt = min(2 * p + (w >> 1) + 1, nt);     // this warp's tile count

    const int qg = qt0 + w * 32 + l31;                // this lane's q row
    bf16x8 qa[4];                                     // Q as B-operand frags
    const bf16* Qrow = Qb + (size_t)bh * 131072 + (size_t)qg * 64 + hi * 8;
#pragma unroll
    for (int ks = 0; ks < 4; ++ks) qa[ks] = *(const bf16x8*)(Qrow + ks * 16);

    f32x16 o0 = {}, o1 = {};                          // O^T accs: [d-sub][q]
    float mr = -1e30f, lr = 0.f;

    const char* Kg = (const char*)(Kb + (size_t)bh * 131072);
    const char* Vg = (const char*)(VTb + (size_t)bh * 131072);
    const int srow = tid >> 3;                 // staged row within 32-row group
    const int sbcol = (tid & 7) * 16;          // byte col within 128B row
    const int ldst = tid * 16;                 // linear LDS dest (gl_lds rule)

#pragma unroll
    for (int g = 0; g < 2; ++g) {
        const int row = g * 32 + srow;
        const int scol = sbcol ^ ((row & 7) << 4);    // inverse-swizzle on SOURCE
        gl_lds16(Kg + row * 128 + scol, &Ks[0][g * 4096 + ldst]);
        gl_lds16(Vg + row * 4096 + scol, &Vs[0][g * 4096 + ldst]);
    }

    const int rbase = l31 * 128 + hi * 16;     // fragment read base (row<32)
    const int rxor = (l31 & 7) << 4;           // swizzle on READ

    int cur = 0;
    for (int kt = 0; kt < nt; ++kt) {
        __syncthreads();  // buf[cur] loads drained; prior reads of buf[cur^1] done
        if (kt + 1 < nt) {
            const int nk = (kt + 1) * 64;
#pragma unroll
            for (int g = 0; g < 2; ++g) {
                const int row = g * 32 + srow;
                const int scol = sbcol ^ ((row & 7) << 4);
                gl_lds16(Kg + (nk + row) * 128 + scol, &Ks[cur ^ 1][g * 4096 + ldst]);
                gl_lds16(Vg + row * 4096 + nk * 2 + scol, &Vs[cur ^ 1][g * 4096 + ldst]);
            }
        }
        if (kt < wt) {
            const int kt0 = kt * 64;
            // S' = K·Q^T : lane holds S[key][q=l31] for 32 keys (16 regs x 2 subtiles)
            f32x16 s0 = {}, s1 = {};
#pragma unroll
            for (int ks = 0; ks < 4; ++ks) {
                bf16x8 ka0 = *(const bf16x8*)&Ks[cur][(rbase + ks * 32) ^ rxor];
                bf16x8 ka1 = *(const bf16x8*)&Ks[cur][(4096 + rbase + ks * 32) ^ rxor];
                s0 = MFMA32(ka0, qa[ks], s0);
                s1 = MFMA32(ka1, qa[ks], s1);
            }
            const bool full = (kt0 + 63 <= qt0 + w * 32) && (kt0 + 64 <= len);
            if (!full) {
                const int kmax = min(qg, len - 1) - kt0;  // local key bound
#pragma unroll
                for (int r = 0; r < 16; ++r) {
                    const int kl = (r & 3) + 8 * (r >> 2) + 4 * hi;
                    if (kl > kmax) s0[r] = -1e30f;
                    if (kl + 32 > kmax) s1[r] = -1e30f;
                }
            }
            // row max: 31 in-lane + 1 half-swap (base-2 domain)
            float mx = s0[0];
#pragma unroll
            for (int r = 1; r < 16; ++r) mx = fmaxf(mx, s0[r]);
#pragma unroll
            for (int r = 0; r < 16; ++r) mx = fmaxf(mx, s1[r]);
            mx = fmaxf(mx, __shfl_xor(mx, 32, 64));
            // defer-max (T13): only rescale when max grew by > 8 (P <= 2^8)
            if (!__all(mx <= mr + 8.f)) {
                const float mn = fmaxf(mr, mx);
                const float al = ex2(mr - mn);
                lr *= al;
#pragma unroll
                for (int r = 0; r < 16; ++r) { o0[r] *= al; o1[r] *= al; }
                mr = mn;
            }
            float sum = 0.f;
#pragma unroll
            for (int r = 0; r < 16; ++r) { s0[r] = ex2(s0[r] - mr); sum += s0[r]; }
#pragma unroll
            for (int r = 0; r < 16; ++r) { s1[r] = ex2(s1[r] - mr); sum += s1[r]; }
            sum += __shfl_xor(sum, 32, 64);
            lr += sum;
            // pack P rows to bf16 pairs: pw[kk*8 + u*2 + h] = keys 32kk+8u+4hi+{2h,2h+1}
            uint32_t pw[16];
#pragma unroll
            for (int u = 0; u < 4; ++u) {
#pragma unroll
                for (int h = 0; h < 2; ++h) {
                    pw[u * 2 + h] = pk2(s0[4 * u + 2 * h], s0[4 * u + 2 * h + 1]);
                    pw[8 + u * 2 + h] = pk2(s1[4 * u + 2 * h], s1[4 * u + 2 * h + 1]);
                }
            }
            // PV: O^T += V^T · P^T, P B-frags assembled via one half-swap per ks
#pragma unroll
            for (int ks = 0; ks < 4; ++ks) {
                const int kk = ks >> 1;
                const int uA2 = (ks & 1) * 4;
                const uint32_t oA0 = pw[kk * 8 + uA2 + 0], oA1 = pw[kk * 8 + uA2 + 1];
                const uint32_t oB0 = pw[kk * 8 + uA2 + 2], oB1 = pw[kk * 8 + uA2 + 3];
                const uint32_t s0w = hi ? oA0 : oB0;
                const uint32_t s1w = hi ? oA1 : oB1;
                const uint32_t r0 = (uint32_t)__shfl_xor((int)s0w, 32, 64);
                const uint32_t r1 = (uint32_t)__shfl_xor((int)s1w, 32, 64);
                union { uint32_t u[4]; bf16x8 v; } pb;
                pb.u[0] = hi ? r0 : oA0;
                pb.u[1] = hi ? r1 : oA1;
                pb.u[2] = hi ? oB0 : r0;
                pb.u[3] = hi ? oB1 : r1;
                bf16x8 va0 = *(const bf16x8*)&Vs[cur][(rbase + ks * 32) ^ rxor];
                bf16x8 va1 = *(const bf16x8*)&Vs[cur][(4096 + rbase + ks * 32) ^ rxor];
                o0 = MFMA32(va0, pb.v, o0);
                o1 = MFMA32(va1, pb.v, o1);
            }
        }
        cur ^= 1;
    }
    const float inv = 1.f / lr;
    bf16* Orow = Ob + (size_t)bh * 131072 + (size_t)qg * 64;
#pragma unroll
    for (int r = 0; r < 16; ++r) {
        const int d = (r & 3) + 8 * (r >> 2) + 4 * hi;
        Orow[d] = (bf16)(o0[r] * inv);
        Orow[32 + d] = (bf16)(o1[r] * inv);
    }
}

extern "C" void kernel_launch(void* const* d_in, const int* in_sizes, int n_in,
                              void* d_out, int out_size, void* d_ws, size_t ws_size,
                              hipStream_t stream) {
    const float* x = (const float*)d_in[0];
    const int* kpm = (const int*)d_in[1];
    // d_in[2] attn_mask: exactly causal triu(k=1) -> applied analytically
    const float* wi = (const float*)d_in[3];
    const float* bi = (const float*)d_in[4];
    const float* wo = (const float*)d_in[5];
    const float* bo = (const float*)d_in[6];
    float* out = (float*)d_out;

    char* ws = (char*)d_ws;
    bf16* Qb  = (bf16*)(ws + (size_t)0);
    bf16* Kb  = (bf16*)(ws + ((size_t)16 << 20));
    bf16* VTb = (bf16*)(ws + ((size_t)32 << 20));
    bf16* xbf = (bf16*)(ws + ((size_t)48 << 20));
    bf16* Ob  = xbf;  // alias: x_bf16 dead after GEMM1
    bf16* wib = (bf16*)(ws + ((size_t)64 << 20));
    bf16* wob = (bf16*)(ws + ((size_t)70 << 20));

    cvt_f32_bf16<<<8192, 256, 0, stream>>>(x, xbf, 8388608);
    cvt_f32_bf16<<<3072, 256, 0, stream>>>(wi, wib, 3145728);
    cvt_f32_bf16<<<1024, 256, 0, stream>>>(wo, wob, 1048576);

    gemm_bt<0><<<dim3(64, 24), 256, 0, stream>>>(xbf, wib, bi, Qb, Kb, VTb, nullptr);
    attn_fwd5<<<1024, 256, 0, stream>>>(Qb, Kb, VTb, kpm, Ob);
    gemm_bt<1><<<dim3(64, 8), 256, 0, stream>>>(Ob, wob, bo, nullptr, nullptr, nullptr, out);
}

// Round 9
// 183.405 us; speedup vs baseline: 1.1178x; 1.0332x over previous
//
#include <hip/hip_runtime.h>
#include <hip/hip_bf16.h>
#include <math.h>

typedef __bf16 bf16;
typedef __attribute__((ext_vector_type(8))) __bf16 bf16x8;
typedef __attribute__((ext_vector_type(4))) __bf16 bf16x4;
typedef __attribute__((ext_vector_type(2))) __bf16 bf16x2;
typedef __attribute__((ext_vector_type(4))) float f32x4;
typedef __attribute__((ext_vector_type(16))) float f32x16;

// Problem constants: B=4, T=2048, E=1024, H=16, HD=64
// g = b*2048+t in [0,8192); bh' = (g&3)*16 + (e>>6); t' = g>>2; d = e&63
// Q/K layout: [bh'][t'][d] flat = bh*131072 + t*64 + d
// VT layout:  [bh'][d][t'] flat = bh*131072 + d*2048 + t
// Attn output flat [bh'][t'][d] IS the row-major (8192,1024) A-matrix of GEMM2.
// Softmax runs base-2: Q pre-scaled by 0.125*log2(e) in the GEMM1 epilogue.

typedef const __attribute__((address_space(1))) void* gas_ptr;
typedef __attribute__((address_space(3))) void* las_ptr;

__device__ __forceinline__ void gl_lds16(const void* g, void* s) {
    __builtin_amdgcn_global_load_lds((gas_ptr)g, (las_ptr)s, 16, 0, 0);
}

__device__ __forceinline__ uint32_t pk2(float a, float b) {
    bf16x2 t; t[0] = (bf16)a; t[1] = (bf16)b;
    return __builtin_bit_cast(uint32_t, t);
}

#if __has_builtin(__builtin_amdgcn_exp2f)
__device__ __forceinline__ float ex2(float x) { return __builtin_amdgcn_exp2f(x); }
#else
__device__ __forceinline__ float ex2(float x) { return exp2f(x); }
#endif

#define MFMA32(a, b, c) __builtin_amdgcn_mfma_f32_32x32x16_bf16(a, b, c, 0, 0, 0)
#define MFMA16(a, b, c) __builtin_amdgcn_mfma_f32_16x16x32_bf16(a, b, c, 0, 0, 0)

__global__ __launch_bounds__(256) void cvt_f32_bf16(const float* __restrict__ in,
                                                    bf16* __restrict__ out, int n) {
    int i = (blockIdx.x * 256 + threadIdx.x) * 4;
    if (i >= n) return;
    float4 v = *(const float4*)(in + i);
    bf16x4 o;
    o[0] = (bf16)v.x; o[1] = (bf16)v.y; o[2] = (bf16)v.z; o[3] = (bf16)v.w;
    *(bf16x4*)(out + i) = o;
}

// ---- shared GEMM core: 128x128 tile, BK=32, double-buffered LDS, ------------
// ---- stage-early + ONE __syncthreads per K-step (T3-lite 2-phase) -----------
// A (Mx1024 bf16 rm) * Bw^T (Nx1024 bf16 rm); acc left in registers.
__device__ __forceinline__ void gemm_core(const bf16* __restrict__ Abase,
                                          const bf16* __restrict__ Bbase,
                                          bf16 (&As)[2][4096], bf16 (&Bs)[2][4096],
                                          f32x4 (&acc)[4][4], int tid) {
    const int l = tid & 63;
    const int w = tid >> 6;
    const int wr = (w >> 1) * 64;
    const int wc = (w & 1) * 64;
    const int fr_row = l & 15;
    const int fr_col = 8 * (l >> 4);

#define STAGE(buf, k0)                                                        \
    {                                                                         \
        _Pragma("unroll")                                                     \
        for (int p = 0; p < 2; ++p) {                                         \
            const int ei = (p * 256 + tid) * 8;                               \
            const int row = ei >> 5;                                          \
            const int col = ei & 31;                                          \
            gl_lds16(Abase + row * 1024 + (k0) + col, (char*)As[buf] + ei * 2);\
            gl_lds16(Bbase + row * 1024 + (k0) + col, (char*)Bs[buf] + ei * 2);\
        }                                                                     \
    }

    STAGE(0, 0);
    __syncthreads();                 // drains prologue loads
    int cur = 0;
    for (int k0 = 0; k0 < 1024; k0 += 32) {
        if (k0 + 32 < 1024) STAGE(cur ^ 1, k0 + 32);   // issue EARLY
        bf16x8 af[4], bfr[4];
#pragma unroll
        for (int m = 0; m < 4; ++m)
            af[m] = *(const bf16x8*)&As[cur][(wr + m * 16 + fr_row) * 32 + fr_col];
#pragma unroll
        for (int n = 0; n < 4; ++n)
            bfr[n] = *(const bf16x8*)&Bs[cur][(wc + n * 16 + fr_row) * 32 + fr_col];
#pragma unroll
        for (int m = 0; m < 4; ++m)
#pragma unroll
            for (int n = 0; n < 4; ++n)
                acc[m][n] = MFMA16(af[m], bfr[n], acc[m][n]);
        __syncthreads();             // one barrier/step: drains my ds_reads (lgkm)
        cur ^= 1;                    // + everyone's stage loads (vm), both hidden
    }
#undef STAGE
}

// GEMM1: x(8192x1024) * in_proj^T(3072x1024) + bias -> scatter Q/K/VT
__global__ __launch_bounds__(256) void gemm_qkv(const bf16* __restrict__ A,
                                                const bf16* __restrict__ Bw,
                                                const float* __restrict__ bias,
                                                bf16* __restrict__ Qb,
                                                bf16* __restrict__ Kb,
                                                bf16* __restrict__ VTb) {
    __shared__ bf16 As[2][4096];
    __shared__ bf16 Bs[2][4096];
    const int tid = threadIdx.x;
    const int l = tid & 63;
    const int w = tid >> 6;
    const int bm0 = blockIdx.x * 128;
    const int bn0 = blockIdx.y * 128;
    f32x4 acc[4][4] = {};
    gemm_core(A + (size_t)bm0 * 1024, Bw + (size_t)bn0 * 1024, As, Bs, acc, tid);

    const int wr = (w >> 1) * 64;
    const int wc = (w & 1) * 64;
    const int rj = (l >> 4) * 4;
    const int cn = l & 15;
    const int sec = bn0 >> 10;
#pragma unroll
    for (int m = 0; m < 4; ++m) {
#pragma unroll
        for (int n = 0; n < 4; ++n) {
            const int gn = bn0 + wc + n * 16 + cn;
            const float bv = bias[gn];
            const int e = gn & 1023;
            const int eh = e >> 6;
            const int ed = e & 63;
#pragma unroll
            for (int j = 0; j < 4; ++j) {
                const int gm = bm0 + wr + m * 16 + rj + j;
                const float v = acc[m][n][j] + bv;
                const int bh = ((gm & 3) << 4) + eh;
                const int t = gm >> 2;
                if (sec == 0) {
                    // 0.125 (hd^-0.5) * log2(e): base-2 softmax domain
                    Qb[bh * 131072 + t * 64 + ed] = (bf16)(v * 0.18033688f);
                } else if (sec == 1) {
                    Kb[bh * 131072 + t * 64 + ed] = (bf16)v;
                } else {
                    VTb[bh * 131072 + ed * 2048 + t] = (bf16)v;
                }
            }
        }
    }
}

// GEMM2: attn(8192x1024) * out_proj^T(1024x1024) + bias -> fp32 out
__global__ __launch_bounds__(256) void gemm_out(const bf16* __restrict__ A,
                                                const bf16* __restrict__ Bw,
                                                const float* __restrict__ bias,
                                                float* __restrict__ Cout) {
    __shared__ bf16 As[2][4096];
    __shared__ bf16 Bs[2][4096];
    const int tid = threadIdx.x;
    const int l = tid & 63;
    const int w = tid >> 6;
    const int bm0 = blockIdx.x * 128;
    const int bn0 = blockIdx.y * 128;
    f32x4 acc[4][4] = {};
    gemm_core(A + (size_t)bm0 * 1024, Bw + (size_t)bn0 * 1024, As, Bs, acc, tid);

    const int wr = (w >> 1) * 64;
    const int wc = (w & 1) * 64;
    const int rj = (l >> 4) * 4;
    const int cn = l & 15;
#pragma unroll
    for (int m = 0; m < 4; ++m) {
#pragma unroll
        for (int n = 0; n < 4; ++n) {
            const int gn = bn0 + wc + n * 16 + cn;
            const float bv = bias[gn];
#pragma unroll
            for (int j = 0; j < 4; ++j) {
                const int gm = bm0 + wr + m * 16 + rj + j;
                Cout[(size_t)gm * 1024 + gn] = acc[m][n][j] + bv;
            }
        }
    }
}

// Flash attention: 4 warps x 32 q-rows (128 q/block), KVBLK=64, 32x32x16 MFMA,
// swapped QK^T (lane owns one q-row), base-2 softmax + defer-max (THR=8),
// __shfl_xor for ALL cross-lane exchanges (permlane32_swap is BANNED: R3/R4
// failed with half-normalized softmax when it was used for reductions).
__global__ __launch_bounds__(256) void attn_fwd5(const bf16* __restrict__ Qb,
                                                 const bf16* __restrict__ Kb,
                                                 const bf16* __restrict__ VTb,
                                                 const int* __restrict__ kpm,
                                                 bf16* __restrict__ Ob) {
    __shared__ __align__(16) char Ks[2][8192];  // [64 keys][64 d] bf16, XOR-swizzled
    __shared__ __align__(16) char Vs[2][8192];  // [64 d][64 keys] bf16, XOR-swizzled
    __shared__ int s_len;

    const int tid = threadIdx.x;
    const int l = tid & 63;
    const int w = tid >> 6;
    const int hi = l >> 5;
    const int l31 = l & 31;

    // Remap: xcd = bid&7 -> 8 bh per XCD (K+V 4MB = one L2); heavy q-tiles first.
    const int bid = blockIdx.x;
    const int j = bid >> 3;
    const int bh = (bid & 7) * 8 + (j & 7);
    const int p = 15 - (j >> 3);
    const int qt0 = p * 128;
    const int c = bh >> 4;

    if (tid == 0) s_len = 2048;
    __syncthreads();
    {
        // monotone tail padding: find first masked index
        const int base = c * 2048 + tid * 8;
        int4 a = *(const int4*)(kpm + base);
        int4 b = *(const int4*)(kpm + base + 4);
        int lm = 2048;
        if (b.w) lm = tid * 8 + 7;
        if (b.z) lm = tid * 8 + 6;
        if (b.y) lm = tid * 8 + 5;
        if (b.x) lm = tid * 8 + 4;
        if (a.w) lm = tid * 8 + 3;
        if (a.z) lm = tid * 8 + 2;
        if (a.y) lm = tid * 8 + 1;
        if (a.x) lm = tid * 8 + 0;
        if (lm < 2048) atomicMin(&s_len, lm);
    }
    __syncthreads();
    const int len = s_len;

    const int nt = min(2 * p + 2, (len + 63) >> 6);   // block tile count
    const int wt = min(2 * p + (w >> 1) + 1, nt);     // this warp's tile count

    const int qg = qt0 + w * 32 + l31;                // this lane's q row
    bf16x8 qa[4];                                     // Q as B-operand frags
    const bf16* Qrow = Qb + (size_t)bh * 131072 + (size_t)qg * 64 + hi * 8;
#pragma unroll
    for (int ks = 0; ks < 4; ++ks) qa[ks] = *(const bf16x8*)(Qrow + ks * 16);

    f32x16 o0 = {}, o1 = {};                          // O^T accs: [d-sub][q]
    float mr = -1e30f, lr = 0.f;

    const char* Kg = (const char*)(Kb + (size_t)bh * 131072);
    const char* Vg = (const char*)(VTb + (size_t)bh * 131072);
    const int srow = tid >> 3;                 // staged row within 32-row group
    const int sbcol = (tid & 7) * 16;          // byte col within 128B row
    const int ldst = tid * 16;                 // linear LDS dest (gl_lds rule)

#pragma unroll
    for (int g = 0; g < 2; ++g) {
        const int row = g * 32 + srow;
        const int scol = sbcol ^ ((row & 7) << 4);    // inverse-swizzle on SOURCE
        gl_lds16(Kg + row * 128 + scol, &Ks[0][g * 4096 + ldst]);
        gl_lds16(Vg + row * 4096 + scol, &Vs[0][g * 4096 + ldst]);
    }

    const int rbase = l31 * 128 + hi * 16;     // fragment read base (row<32)
    const int rxor = (l31 & 7) << 4;           // swizzle on READ

    int cur = 0;
    for (int kt = 0; kt < nt; ++kt) {
        __syncthreads();  // buf[cur] loads drained; prior reads of buf[cur^1] done
        if (kt + 1 < nt) {
            const int nk = (kt + 1) * 64;
#pragma unroll
            for (int g = 0; g < 2; ++g) {
                const int row = g * 32 + srow;
                const int scol = sbcol ^ ((row & 7) << 4);
                gl_lds16(Kg + (nk + row) * 128 + scol, &Ks[cur ^ 1][g * 4096 + ldst]);
                gl_lds16(Vg + row * 4096 + nk * 2 + scol, &Vs[cur ^ 1][g * 4096 + ldst]);
            }
        }
        if (kt < wt) {
            const int kt0 = kt * 64;
            // S' = K·Q^T : lane holds S[key][q=l31] for 32 keys (16 regs x 2 subtiles)
            f32x16 s0 = {}, s1 = {};
#pragma unroll
            for (int ks = 0; ks < 4; ++ks) {
                bf16x8 ka0 = *(const bf16x8*)&Ks[cur][(rbase + ks * 32) ^ rxor];
                bf16x8 ka1 = *(const bf16x8*)&Ks[cur][(4096 + rbase + ks * 32) ^ rxor];
                s0 = MFMA32(ka0, qa[ks], s0);
                s1 = MFMA32(ka1, qa[ks], s1);
            }
            const bool full = (kt0 + 63 <= qt0 + w * 32) && (kt0 + 64 <= len);
            if (!full) {
                const int kmax = min(qg, len - 1) - kt0;  // local key bound
#pragma unroll
                for (int r = 0; r < 16; ++r) {
                    const int kl = (r & 3) + 8 * (r >> 2) + 4 * hi;
                    if (kl > kmax) s0[r] = -1e30f;
                    if (kl + 32 > kmax) s1[r] = -1e30f;
                }
            }
            // row max: 31 in-lane + 1 half-swap (base-2 domain)
            float mx = s0[0];
#pragma unroll
            for (int r = 1; r < 16; ++r) mx = fmaxf(mx, s0[r]);
#pragma unroll
            for (int r = 0; r < 16; ++r) mx = fmaxf(mx, s1[r]);
            mx = fmaxf(mx, __shfl_xor(mx, 32, 64));
            // defer-max (T13): only rescale when max grew by > 8 (P <= 2^8)
            if (!__all(mx <= mr + 8.f)) {
                const float mn = fmaxf(mr, mx);
                const float al = ex2(mr - mn);
                lr *= al;
#pragma unroll
                for (int r = 0; r < 16; ++r) { o0[r] *= al; o1[r] *= al; }
                mr = mn;
            }
            float sum = 0.f;
#pragma unroll
            for (int r = 0; r < 16; ++r) { s0[r] = ex2(s0[r] - mr); sum += s0[r]; }
#pragma unroll
            for (int r = 0; r < 16; ++r) { s1[r] = ex2(s1[r] - mr); sum += s1[r]; }
            sum += __shfl_xor(sum, 32, 64);
            lr += sum;
            // pack P rows to bf16 pairs: pw[kk*8 + u*2 + h] = keys 32kk+8u+4hi+{2h,2h+1}
            uint32_t pw[16];
#pragma unroll
            for (int u = 0; u < 4; ++u) {
#pragma unroll
                for (int h = 0; h < 2; ++h) {
                    pw[u * 2 + h] = pk2(s0[4 * u + 2 * h], s0[4 * u + 2 * h + 1]);
                    pw[8 + u * 2 + h] = pk2(s1[4 * u + 2 * h], s1[4 * u + 2 * h + 1]);
                }
            }
            // PV: O^T += V^T · P^T, P B-frags assembled via one half-swap per ks
#pragma unroll
            for (int ks = 0; ks < 4; ++ks) {
                const int kk = ks >> 1;
                const int uA2 = (ks & 1) * 4;
                const uint32_t oA0 = pw[kk * 8 + uA2 + 0], oA1 = pw[kk * 8 + uA2 + 1];
                const uint32_t oB0 = pw[kk * 8 + uA2 + 2], oB1 = pw[kk * 8 + uA2 + 3];
                const uint32_t s0w = hi ? oA0 : oB0;
                const uint32_t s1w = hi ? oA1 : oB1;
                const uint32_t r0 = (uint32_t)__shfl_xor((int)s0w, 32, 64);
                const uint32_t r1 = (uint32_t)__shfl_xor((int)s1w, 32, 64);
                union { uint32_t u[4]; bf16x8 v; } pb;
                pb.u[0] = hi ? r0 : oA0;
                pb.u[1] = hi ? r1 : oA1;
                pb.u[2] = hi ? oB0 : r0;
                pb.u[3] = hi ? oB1 : r1;
                bf16x8 va0 = *(const bf16x8*)&Vs[cur][(rbase + ks * 32) ^ rxor];
                bf16x8 va1 = *(const bf16x8*)&Vs[cur][(4096 + rbase + ks * 32) ^ rxor];
                o0 = MFMA32(va0, pb.v, o0);
                o1 = MFMA32(va1, pb.v, o1);
            }
        }
        cur ^= 1;
    }
    const float inv = 1.f / lr;
    bf16* Orow = Ob + (size_t)bh * 131072 + (size_t)qg * 64;
#pragma unroll
    for (int r = 0; r < 16; ++r) {
        const int d = (r & 3) + 8 * (r >> 2) + 4 * hi;
        Orow[d] = (bf16)(o0[r] * inv);
        Orow[32 + d] = (bf16)(o1[r] * inv);
    }
}

extern "C" void kernel_launch(void* const* d_in, const int* in_sizes, int n_in,
                              void* d_out, int out_size, void* d_ws, size_t ws_size,
                              hipStream_t stream) {
    const float* x = (const float*)d_in[0];
    const int* kpm = (const int*)d_in[1];
    // d_in[2] attn_mask: exactly causal triu(k=1) -> applied analytically
    const float* wi = (const float*)d_in[3];
    const float* bi = (const float*)d_in[4];
    const float* wo = (const float*)d_in[5];
    const float* bo = (const float*)d_in[6];
    float* out = (float*)d_out;

    char* ws = (char*)d_ws;
    bf16* Qb  = (bf16*)(ws + (size_t)0);
    bf16* Kb  = (bf16*)(ws + ((size_t)16 << 20));
    bf16* VTb = (bf16*)(ws + ((size_t)32 << 20));
    bf16* xbf = (bf16*)(ws + ((size_t)48 << 20));
    bf16* Ob  = xbf;  // alias: x_bf16 dead after GEMM1
    bf16* wib = (bf16*)(ws + ((size_t)64 << 20));
    bf16* wob = (bf16*)(ws + ((size_t)70 << 20));

    cvt_f32_bf16<<<8192, 256, 0, stream>>>(x, xbf, 8388608);
    cvt_f32_bf16<<<3072, 256, 0, stream>>>(wi, wib, 3145728);
    cvt_f32_bf16<<<1024, 256, 0, stream>>>(wo, wob, 1048576);

    gemm_qkv<<<dim3(64, 24), 256, 0, stream>>>(xbf, wib, bi, Qb, Kb, VTb);
    attn_fwd5<<<1024, 256, 0, stream>>>(Qb, Kb, VTb, kpm, Ob);
    gemm_out<<<dim3(64, 8), 256, 0, stream>>>(Ob, wob, bo, out);
}